// Round 5
// baseline (488.466 us; speedup 1.0000x reference)
//
#include <hip/hip_runtime.h>
#include <math.h>

#define B_ 2
#define W_ 2048
#define C_ 1024
#define H_ 16
#define K_ 64
#define LN_EPS 1e-5f

typedef __attribute__((ext_vector_type(8))) short short8;   // 8 bf16 (4 VGPRs)
typedef __attribute__((ext_vector_type(4))) short short4v;  // 4 bf16 (2 VGPRs)
typedef __attribute__((ext_vector_type(4))) float float4v;  // MFMA C/D frag

__device__ inline unsigned short f2bf(float f) {  // RNE float->bf16
  unsigned u = __float_as_uint(f);
  u += 0x7fffu + ((u >> 16) & 1u);
  return (unsigned short)(u >> 16);
}

__device__ __forceinline__ float4v mfma_16x16x16_bf16(short4v a, short4v b, float4v c) {
#if __has_builtin(__builtin_amdgcn_mfma_f32_16x16x16bf16_1k)
  return __builtin_amdgcn_mfma_f32_16x16x16bf16_1k(a, b, c, 0, 0, 0);
#else
  asm volatile("v_mfma_f32_16x16x16_bf16 %0, %1, %2, %0\n\ts_nop 7\n\ts_nop 4"
               : "+v"(c) : "v"(a), "v"(b));
  return c;
#endif
}

__device__ __forceinline__ void gload_lds16(const short* g, short* l) {
  __builtin_amdgcn_global_load_lds(
      (const __attribute__((address_space(1))) void*)g,
      (__attribute__((address_space(3))) void*)l, 16, 0, 0);
}

// ---------------------------------------------------------------------------
// Block-wide sum over 256 threads (4 waves of 64)
// ---------------------------------------------------------------------------
__device__ inline float block_sum(float val) {
  __shared__ float sb[4];
  #pragma unroll
  for (int o = 32; o > 0; o >>= 1) val += __shfl_down(val, o, 64);
  int lane = threadIdx.x & 63, wid = threadIdx.x >> 6;
  if (lane == 0) sb[wid] = val;
  __syncthreads();
  float r = sb[0] + sb[1] + sb[2] + sb[3];
  __syncthreads();
  return r;
}

// ---------------------------------------------------------------------------
// LayerNorm -> bf16 output. One block per row; handles both seq1 and seq2.
// ---------------------------------------------------------------------------
__global__ __launch_bounds__(256) void ln_kernel(
    const float* __restrict__ seq1, const float* __restrict__ seq2,
    const float* __restrict__ gamma, const float* __restrict__ beta,
    short* __restrict__ x1b, short* __restrict__ x2b) {
  int row = blockIdx.x;
  const int nrows = B_ * W_;
  bool first = row < nrows;
  const float* src = first ? seq1 : seq2;
  short* dst = first ? x1b : x2b;
  int r = first ? row : row - nrows;

  const float4* p = (const float4*)(src + (size_t)r * C_);
  float4 v = p[threadIdx.x];
  float mean = block_sum(v.x + v.y + v.z + v.w) * (1.0f / C_);
  float dx = v.x - mean, dy = v.y - mean, dz = v.z - mean, dw = v.w - mean;
  float var = block_sum(dx * dx + dy * dy + dz * dz + dw * dw) * (1.0f / C_);
  float rstd = rsqrtf(var + LN_EPS);

  float4 g = ((const float4*)gamma)[threadIdx.x];
  float4 b = ((const float4*)beta)[threadIdx.x];
  uint2 o;
  o.x = (unsigned)f2bf(dx * rstd * g.x + b.x) |
        ((unsigned)f2bf(dy * rstd * g.y + b.y) << 16);
  o.y = (unsigned)f2bf(dz * rstd * g.z + b.z) |
        ((unsigned)f2bf(dw * rstd * g.w + b.w) << 16);
  ((uint2*)(dst + (size_t)r * C_))[threadIdx.x] = o;
}

// ---------------------------------------------------------------------------
// Weight prep: proj [H,C,K] fp32 -> B^T bf16 [H*K rows][C cols], q scaled by
// 1/sqrt(K) (exact pow2). grid=(C/64, H, 3), block=256, LDS transpose.
// ---------------------------------------------------------------------------
__global__ __launch_bounds__(256) void wprep_proj_kernel(
    const float* __restrict__ qp, const float* __restrict__ kp,
    const float* __restrict__ vp,
    short* __restrict__ wqt, short* __restrict__ wkt, short* __restrict__ wvt) {
  int cb = blockIdx.x, h = blockIdx.y, which = blockIdx.z;
  const float* P = (which == 0 ? qp : (which == 1 ? kp : vp)) + (size_t)h * C_ * K_;
  short* Wt = (which == 0 ? wqt : (which == 1 ? wkt : wvt));
  float scale = (which == 0) ? 0.125f : 1.0f;

  __shared__ float Ls[64][65];
  int t = threadIdx.x;
  {
    int cr = t >> 2, ks = (t & 3) * 16;
    const float* src = P + (size_t)(cb * 64 + cr) * K_ + ks;
    #pragma unroll
    for (int j = 0; j < 4; ++j) {
      float4 v = *(const float4*)(src + j * 4);
      Ls[cr][ks + j * 4 + 0] = v.x; Ls[cr][ks + j * 4 + 1] = v.y;
      Ls[cr][ks + j * 4 + 2] = v.z; Ls[cr][ks + j * 4 + 3] = v.w;
    }
  }
  __syncthreads();
  int kr = t >> 2, cs = (t & 3) * 16;
  unsigned u[8];
  #pragma unroll
  for (int i = 0; i < 8; ++i) {
    float a = Ls[cs + 2 * i][kr] * scale;
    float b = Ls[cs + 2 * i + 1][kr] * scale;
    u[i] = (unsigned)f2bf(a) | ((unsigned)f2bf(b) << 16);
  }
  short* dst = Wt + ((size_t)h * 64 + kr) * C_ + cb * 64 + cs;
  uint4 p0; p0.x = u[0]; p0.y = u[1]; p0.z = u[2]; p0.w = u[3];
  uint4 p1; p1.x = u[4]; p1.y = u[5]; p1.z = u[6]; p1.w = u[7];
  *(uint4*)dst = p0;
  *(uint4*)(dst + 8) = p1;
}

// Mixer weight: plain fp32 -> bf16 (already in B^T form: out@W.T uses W[n][c]).
__global__ __launch_bounds__(256) void wprep_mix_kernel(
    const float* __restrict__ wm, short* __restrict__ wmb) {
  int gid = blockIdx.x * 256 + threadIdx.x;
  float4 v = ((const float4*)wm)[gid];
  uint2 o;
  o.x = (unsigned)f2bf(v.x) | ((unsigned)f2bf(v.y) << 16);
  o.y = (unsigned)f2bf(v.z) | ((unsigned)f2bf(v.w) << 16);
  ((uint2*)wmb)[gid] = o;
}

// ---------------------------------------------------------------------------
// bf16 MFMA GEMM core: C[128x128] tile of A[*,1024] x Bt[*,1024]^T.
// 256 threads = 4 waves (2x2), 16x16x32 MFMA, 4x4 frags/wave, BK=64.
// global_load_lds width-16 staging; XOR-swizzled LDS (conflict-free frags).
// ---------------------------------------------------------------------------
__device__ __forceinline__ void gemm_core(
    const short* __restrict__ A, const short* __restrict__ Bt,
    int arow0, int brow0, short* As, short* Bs, float4v acc[4][4]) {
  int tid = threadIdx.x;
  int wave = tid >> 6, lane = tid & 63;
  int lr = lane >> 3, lc = lane & 7;
  int sc = lc ^ lr;                       // swizzled global chunk for staging
  int wr = wave >> 1, wc = wave & 1;
  int lg = lane >> 4, ll = lane & 15;

  #pragma unroll
  for (int mi = 0; mi < 4; ++mi)
    #pragma unroll
    for (int ni = 0; ni < 4; ++ni) {
      acc[mi][ni][0] = 0.f; acc[mi][ni][1] = 0.f;
      acc[mi][ni][2] = 0.f; acc[mi][ni][3] = 0.f;
    }

  for (int k0 = 0; k0 < C_; k0 += 64) {
    __syncthreads();
    #pragma unroll
    for (int j = 0; j < 4; ++j) {
      int seg = wave * 4 + j;            // 8-row segment of the 128-row tile
      int r = seg * 8 + lr;
      gload_lds16(A + (size_t)(arow0 + r) * C_ + k0 + sc * 8, As + seg * 512);
      gload_lds16(Bt + (size_t)(brow0 + r) * C_ + k0 + sc * 8, Bs + seg * 512);
    }
    __syncthreads();
    #pragma unroll
    for (int kc = 0; kc < 2; ++kc) {
      int cc = kc * 4 + lg;
      short8 af[4], bf[4];
      #pragma unroll
      for (int mi = 0; mi < 4; ++mi) {
        int m = wr * 64 + mi * 16 + ll;
        af[mi] = *(const short8*)&As[m * 64 + ((cc ^ (m & 7)) << 3)];
      }
      #pragma unroll
      for (int ni = 0; ni < 4; ++ni) {
        int n = wc * 64 + ni * 16 + ll;
        bf[ni] = *(const short8*)&Bs[n * 64 + ((cc ^ (n & 7)) << 3)];
      }
      #pragma unroll
      for (int mi = 0; mi < 4; ++mi)
        #pragma unroll
        for (int ni = 0; ni < 4; ++ni)
          acc[mi][ni] = __builtin_amdgcn_mfma_f32_16x16x32_bf16(
              af[mi], bf[ni], acc[mi][ni], 0, 0, 0);
    }
  }
}

// ---------------------------------------------------------------------------
// QKV GEMMs, fused in grid.z: z=0 Q=x1@Wq^T, z=1 K=x2@Wk^T,
// z=2 V^T = Wv x2^T (operand-swapped so stores into [B,H,K,W] coalesce).
// Outputs bf16. grid=(32,8,3).
// ---------------------------------------------------------------------------
__global__ __launch_bounds__(256, 3) void gemm_qkv_kernel(
    const short* __restrict__ x1b, const short* __restrict__ x2b,
    const short* __restrict__ wqt, const short* __restrict__ wkt,
    const short* __restrict__ wvt,
    short* __restrict__ qb, short* __restrict__ kb, short* __restrict__ vtb) {
  __shared__ short As[128 * 64], Bs[128 * 64];
  int z = blockIdx.z;
  const short *A, *Bt;
  int arow0, brow0;
  if (z == 0)      { A = x1b; Bt = wqt; arow0 = blockIdx.x * 128; brow0 = blockIdx.y * 128; }
  else if (z == 1) { A = x2b; Bt = wkt; arow0 = blockIdx.x * 128; brow0 = blockIdx.y * 128; }
  else             { A = wvt; Bt = x2b; arow0 = blockIdx.y * 128; brow0 = blockIdx.x * 128; }

  float4v acc[4][4];
  gemm_core(A, Bt, arow0, brow0, As, Bs, acc);

  int wave = threadIdx.x >> 6, lane = threadIdx.x & 63;
  int wr = wave >> 1, wc = wave & 1, lg = lane >> 4, ll = lane & 15;
  if (z <= 1) {
    short* O = (z == 0) ? qb : kb;
    #pragma unroll
    for (int mi = 0; mi < 4; ++mi)
      #pragma unroll
      for (int ni = 0; ni < 4; ++ni) {
        int n = brow0 + wc * 64 + ni * 16 + ll;       // h*64+k
        int h = n >> 6, kk = n & 63;
        #pragma unroll
        for (int r2 = 0; r2 < 4; ++r2) {
          int m = arow0 + wr * 64 + mi * 16 + lg * 4 + r2;  // seq index
          int b = m >> 11, w = m & (W_ - 1);
          O[((size_t)(b * H_ + h) * W_ + w) * K_ + kk] = (short)f2bf(acc[mi][ni][r2]);
        }
      }
  } else {
    #pragma unroll
    for (int mi = 0; mi < 4; ++mi)
      #pragma unroll
      for (int ni = 0; ni < 4; ++ni) {
        int n = brow0 + wc * 64 + ni * 16 + ll;       // seq index
        int b = n >> 11, w = n & (W_ - 1);
        #pragma unroll
        for (int r2 = 0; r2 < 4; ++r2) {
          int m = arow0 + wr * 64 + mi * 16 + lg * 4 + r2;  // h*64+k
          int h = m >> 6, kk = m & 63;
          vtb[((size_t)(b * H_ + h) * K_ + kk) * W_ + w] = (short)f2bf(acc[mi][ni][r2]);
        }
      }
  }
}

// ---------------------------------------------------------------------------
// Mixer GEMM: out[4096,1024] fp32 = attnb @ wmb^T + bias. grid=(32,8).
// ---------------------------------------------------------------------------
__global__ __launch_bounds__(256, 3) void gemm_mix_kernel(
    const short* __restrict__ attnb, const short* __restrict__ wmb,
    const float* __restrict__ bias, float* __restrict__ out) {
  __shared__ short As[128 * 64], Bs[128 * 64];
  int arow0 = blockIdx.x * 128, brow0 = blockIdx.y * 128;
  float4v acc[4][4];
  gemm_core(attnb, wmb, arow0, brow0, As, Bs, acc);

  int wave = threadIdx.x >> 6, lane = threadIdx.x & 63;
  int wr = wave >> 1, wc = wave & 1, lg = lane >> 4, ll = lane & 15;
  #pragma unroll
  for (int mi = 0; mi < 4; ++mi)
    #pragma unroll
    for (int ni = 0; ni < 4; ++ni) {
      int n = brow0 + wc * 64 + ni * 16 + ll;
      float bv = bias[n];
      #pragma unroll
      for (int r2 = 0; r2 < 4; ++r2) {
        int m = arow0 + wr * 64 + mi * 16 + lg * 4 + r2;
        out[(size_t)m * C_ + n] = acc[mi][ni][r2] + bv;
      }
    }
}

// ---------------------------------------------------------------------------
// Causal flash attention, transposed-S scheme. grid=(64, B*H), block=128
// (2 waves x 16 queries). Per 64-key tile:
//   S^T = K·Q^T (4x2 mfma 16x16x32): C-layout col = QUERY -> softmax is
//   lane-local (16 scores/lane, one query/lane; 2 shuffles per stat).
//   P^T C-layout regs are directly the B-operand of mfma_f32_16x16x16_bf16:
//   O^T += V^T·P^T with zero LDS / zero cross-lane in the K-loop.
// Epilogue: per-wave LDS transpose -> coalesced bf16 [B,W,C] stores.
// ---------------------------------------------------------------------------
__global__ __launch_bounds__(128) void attn_mfma_kernel(
    const short* __restrict__ q, const short* __restrict__ k,
    const short* __restrict__ vt, short* __restrict__ out) {
  int bh = blockIdx.y;
  int b = bh >> 4, h = bh & 15;
  int qb = (int)gridDim.x - 1 - (int)blockIdx.x;  // 0..63, heavy tiles first
  int wave = threadIdx.x >> 6;                    // 0..1
  int lane = threadIdx.x & 63;
  int lg = lane >> 4, ll = lane & 15;
  int q0 = qb * 32 + wave * 16;                   // wave's query base
  int myq = q0 + ll;                              // this lane's query

  const short* qp = q + (size_t)bh * W_ * K_;
  const short* kp = k + (size_t)bh * W_ * K_;
  const short* vb = vt + (size_t)bh * K_ * W_;

  // Q as B-operand (Q^T): lane holds Q[myq][kc*32 + lg*8 + j]
  short8 bq[2];
  #pragma unroll
  for (int kc = 0; kc < 2; ++kc)
    bq[kc] = *(const short8*)(qp + (size_t)myq * K_ + kc * 32 + lg * 8);

  float4v o[4];
  #pragma unroll
  for (int ct = 0; ct < 4; ++ct) { o[ct][0] = 0.f; o[ct][1] = 0.f; o[ct][2] = 0.f; o[ct][3] = 0.f; }
  float m_i = -INFINITY, l_i = 0.0f;

  int nkt = (qb >> 1) + 1;   // 64-key tiles covering keys <= q0+31

  for (int kt = 0; kt < nkt; ++kt) {
    const short* kbase = kp + (size_t)kt * 64 * K_;
    // ---- S^T tiles: st[mt] holds S[query=myq][key=kt*64+mt*16+lg*4+r] ----
    float4v st[4];
    #pragma unroll
    for (int mt = 0; mt < 4; ++mt) {
      st[mt][0] = 0.f; st[mt][1] = 0.f; st[mt][2] = 0.f; st[mt][3] = 0.f;
      #pragma unroll
      for (int kc = 0; kc < 2; ++kc) {
        short8 ak = *(const short8*)(kbase + (size_t)(mt * 16 + ll) * K_ + kc * 32 + lg * 8);
        st[mt] = __builtin_amdgcn_mfma_f32_16x16x32_bf16(ak, bq[kc], st[mt], 0, 0, 0);
      }
    }
    // ---- V^T A-frags (independent: issue early to cover softmax) ----
    short4v va[4][4];
    #pragma unroll
    for (int ct = 0; ct < 4; ++ct)
      #pragma unroll
      for (int t = 0; t < 4; ++t)
        va[ct][t] = *(const short4v*)(vb + (size_t)(ct * 16 + ll) * W_ +
                                      kt * 64 + t * 16 + lg * 4);
    // ---- causal mask (last tile only) ----
    if (kt == nkt - 1) {
      #pragma unroll
      for (int mt = 0; mt < 4; ++mt)
        #pragma unroll
        for (int r = 0; r < 4; ++r) {
          int key = kt * 64 + mt * 16 + lg * 4 + r;
          if (key > myq) st[mt][r] = -INFINITY;
        }
    }
    // ---- lane-local online softmax (one query per lane) ----
    float tmax = -INFINITY;
    #pragma unroll
    for (int mt = 0; mt < 4; ++mt)
      #pragma unroll
      for (int r = 0; r < 4; ++r) tmax = fmaxf(tmax, st[mt][r]);
    tmax = fmaxf(tmax, __shfl_xor(tmax, 16, 64));
    tmax = fmaxf(tmax, __shfl_xor(tmax, 32, 64));
    float nm = fmaxf(m_i, tmax);
    float alpha = __expf(m_i - nm);   // first iter: exp(-inf)=0
    m_i = nm;
    float p[4][4];
    float ps = 0.f;
    #pragma unroll
    for (int mt = 0; mt < 4; ++mt)
      #pragma unroll
      for (int r = 0; r < 4; ++r) {
        float e = __expf(st[mt][r] - nm);
        p[mt][r] = e;
        ps += e;
      }
    ps += __shfl_xor(ps, 16, 64);
    ps += __shfl_xor(ps, 32, 64);
    l_i = l_i * alpha + ps;
    #pragma unroll
    for (int ct = 0; ct < 4; ++ct) {
      o[ct][0] *= alpha; o[ct][1] *= alpha; o[ct][2] *= alpha; o[ct][3] *= alpha;
    }
    // ---- P^T B-frags (bf16) straight from registers ----
    short4v pb[4];
    #pragma unroll
    for (int t = 0; t < 4; ++t) {
      pb[t][0] = (short)f2bf(p[t][0]); pb[t][1] = (short)f2bf(p[t][1]);
      pb[t][2] = (short)f2bf(p[t][2]); pb[t][3] = (short)f2bf(p[t][3]);
    }
    // ---- O^T += V^T · P^T ----
    #pragma unroll
    for (int ct = 0; ct < 4; ++ct)
      #pragma unroll
      for (int t = 0; t < 4; ++t)
        o[ct] = mfma_16x16x16_bf16(va[ct][t], pb[t], o[ct]);
  }

  // ---- epilogue: normalize; per-wave LDS transpose; coalesced bf16 store ----
  float inv = 1.0f / l_i;            // per-lane (one query per lane)
  __shared__ short tl[2][16][72];    // [wave][query][chan], +8 pad
  short* tw = &tl[wave][0][0];
  #pragma unroll
  for (int ct = 0; ct < 4; ++ct) {
    unsigned w0 = (unsigned)f2bf(o[ct][0] * inv) | ((unsigned)f2bf(o[ct][1] * inv) << 16);
    unsigned w1 = (unsigned)f2bf(o[ct][2] * inv) | ((unsigned)f2bf(o[ct][3] * inv) << 16);
    uint2 pk; pk.x = w0; pk.y = w1;
    *(uint2*)(tw + ll * 72 + ct * 16 + lg * 4) = pk;
  }
  __builtin_amdgcn_s_waitcnt(0xC07F);  // lgkmcnt(0): wave-private LDS ordering
  #pragma unroll
  for (int pss = 0; pss < 2; ++pss) {
    int qq = pss * 8 + (lane >> 3);
    int ck = lane & 7;
    uint4 vv = *(const uint4*)(tw + qq * 72 + ck * 8);
    *(uint4*)(out + ((size_t)(b * W_ + q0 + qq)) * C_ + h * K_ + ck * 8) = vv;
  }
}

// ---------------------------------------------------------------------------
extern "C" void kernel_launch(void* const* d_in, const int* in_sizes, int n_in,
                              void* d_out, int out_size, void* d_ws, size_t ws_size,
                              hipStream_t stream) {
  const float* seq1  = (const float*)d_in[0];
  const float* seq2  = (const float*)d_in[1];
  const float* gamma = (const float*)d_in[2];
  const float* beta  = (const float*)d_in[3];
  const float* qp    = (const float*)d_in[4];
  const float* kp    = (const float*)d_in[5];
  const float* vp    = (const float*)d_in[6];
  const float* wm    = (const float*)d_in[7];
  const float* mb    = (const float*)d_in[8];
  float* out = (float*)d_out;

  char* ws = (char*)d_ws;
  const size_t NROW = (size_t)B_ * W_;               // 4096
  const size_t XB = NROW * C_ * sizeof(short);       // 8 MB bf16 activation buf
  const size_t WB = (size_t)C_ * C_ * sizeof(short); // 2 MB bf16 weight buf
  short* x1b = (short*)(ws);
  short* x2b = (short*)(ws + XB);
  short* qb  = (short*)(ws + 2 * XB);
  short* kb  = (short*)(ws + 3 * XB);
  short* vtb = (short*)(ws + 4 * XB);
  short* wqt = (short*)(ws + 5 * XB);
  short* wkt = (short*)(ws + 5 * XB + WB);
  short* wvt = (short*)(ws + 5 * XB + 2 * WB);
  short* wmb = (short*)(ws + 5 * XB + 3 * WB);
  short* attnb = (short*)(ws + 5 * XB + 4 * WB);

  wprep_proj_kernel<<<dim3(C_ / 64, H_, 3), dim3(256), 0, stream>>>(
      qp, kp, vp, wqt, wkt, wvt);
  wprep_mix_kernel<<<dim3(C_ * C_ / 1024), dim3(256), 0, stream>>>(wm, wmb);
  ln_kernel<<<dim3(2 * (unsigned)NROW), dim3(256), 0, stream>>>(
      seq1, seq2, gamma, beta, x1b, x2b);
  gemm_qkv_kernel<<<dim3(32, 8, 3), dim3(256), 0, stream>>>(
      x1b, x2b, wqt, wkt, wvt, qb, kb, vtb);
  attn_mfma_kernel<<<dim3(64, B_ * H_), dim3(128), 0, stream>>>(
      qb, kb, vtb, attnb);
  gemm_mix_kernel<<<dim3(32, 8), dim3(256), 0, stream>>>(attnb, wmb, mb, out);
}

// Round 6
// 445.331 us; speedup vs baseline: 1.0969x; 1.0969x over previous
//
#include <hip/hip_runtime.h>
#include <math.h>

#define B_ 2
#define W_ 2048
#define C_ 1024
#define H_ 16
#define K_ 64
#define LN_EPS 1e-5f
#define SEG_ 4          // key-split segments (512 keys each)
#define TPS 8           // 64-key tiles per segment

typedef __attribute__((ext_vector_type(8))) short short8;   // 8 bf16 (4 VGPRs)
typedef __attribute__((ext_vector_type(4))) short short4v;  // 4 bf16 (2 VGPRs)
typedef __attribute__((ext_vector_type(4))) float float4v;  // MFMA C/D frag

__device__ inline unsigned short f2bf(float f) {  // RNE float->bf16
  unsigned u = __float_as_uint(f);
  u += 0x7fffu + ((u >> 16) & 1u);
  return (unsigned short)(u >> 16);
}
__device__ inline float bf2f(short s) {
  return __uint_as_float(((unsigned)(unsigned short)s) << 16);
}

__device__ __forceinline__ float4v mfma_16x16x16_bf16(short4v a, short4v b, float4v c) {
#if __has_builtin(__builtin_amdgcn_mfma_f32_16x16x16bf16_1k)
  return __builtin_amdgcn_mfma_f32_16x16x16bf16_1k(a, b, c, 0, 0, 0);
#else
  asm volatile("v_mfma_f32_16x16x16_bf16 %0, %1, %2, %0\n\ts_nop 7\n\ts_nop 4"
               : "+v"(c) : "v"(a), "v"(b));
  return c;
#endif
}

__device__ __forceinline__ void gload_lds16(const short* g, short* l) {
  __builtin_amdgcn_global_load_lds(
      (const __attribute__((address_space(1))) void*)g,
      (__attribute__((address_space(3))) void*)l, 16, 0, 0);
}

// ---------------------------------------------------------------------------
// Block-wide sum over 256 threads (4 waves of 64)
// ---------------------------------------------------------------------------
__device__ inline float block_sum(float val) {
  __shared__ float sb[4];
  #pragma unroll
  for (int o = 32; o > 0; o >>= 1) val += __shfl_down(val, o, 64);
  int lane = threadIdx.x & 63, wid = threadIdx.x >> 6;
  if (lane == 0) sb[wid] = val;
  __syncthreads();
  float r = sb[0] + sb[1] + sb[2] + sb[3];
  __syncthreads();
  return r;
}

// ---------------------------------------------------------------------------
// LayerNorm -> bf16 output. One block per row; handles both seq1 and seq2.
// ---------------------------------------------------------------------------
__global__ __launch_bounds__(256) void ln_kernel(
    const float* __restrict__ seq1, const float* __restrict__ seq2,
    const float* __restrict__ gamma, const float* __restrict__ beta,
    short* __restrict__ x1b, short* __restrict__ x2b) {
  int row = blockIdx.x;
  const int nrows = B_ * W_;
  bool first = row < nrows;
  const float* src = first ? seq1 : seq2;
  short* dst = first ? x1b : x2b;
  int r = first ? row : row - nrows;

  const float4* p = (const float4*)(src + (size_t)r * C_);
  float4 v = p[threadIdx.x];
  float mean = block_sum(v.x + v.y + v.z + v.w) * (1.0f / C_);
  float dx = v.x - mean, dy = v.y - mean, dz = v.z - mean, dw = v.w - mean;
  float var = block_sum(dx * dx + dy * dy + dz * dz + dw * dw) * (1.0f / C_);
  float rstd = rsqrtf(var + LN_EPS);

  float4 g = ((const float4*)gamma)[threadIdx.x];
  float4 b = ((const float4*)beta)[threadIdx.x];
  uint2 o;
  o.x = (unsigned)f2bf(dx * rstd * g.x + b.x) |
        ((unsigned)f2bf(dy * rstd * g.y + b.y) << 16);
  o.y = (unsigned)f2bf(dz * rstd * g.z + b.z) |
        ((unsigned)f2bf(dw * rstd * g.w + b.w) << 16);
  ((uint2*)(dst + (size_t)r * C_))[threadIdx.x] = o;
}

// ---------------------------------------------------------------------------
// Weight prep: proj [H,C,K] fp32 -> B^T bf16 [H*K rows][C cols], q scaled by
// 1/sqrt(K) (exact pow2). grid=(C/64, H, 3), block=256, LDS transpose.
// ---------------------------------------------------------------------------
__global__ __launch_bounds__(256) void wprep_proj_kernel(
    const float* __restrict__ qp, const float* __restrict__ kp,
    const float* __restrict__ vp,
    short* __restrict__ wqt, short* __restrict__ wkt, short* __restrict__ wvt) {
  int cb = blockIdx.x, h = blockIdx.y, which = blockIdx.z;
  const float* P = (which == 0 ? qp : (which == 1 ? kp : vp)) + (size_t)h * C_ * K_;
  short* Wt = (which == 0 ? wqt : (which == 1 ? wkt : wvt));
  float scale = (which == 0) ? 0.125f : 1.0f;

  __shared__ float Ls[64][65];
  int t = threadIdx.x;
  {
    int cr = t >> 2, ks = (t & 3) * 16;
    const float* src = P + (size_t)(cb * 64 + cr) * K_ + ks;
    #pragma unroll
    for (int j = 0; j < 4; ++j) {
      float4 v = *(const float4*)(src + j * 4);
      Ls[cr][ks + j * 4 + 0] = v.x; Ls[cr][ks + j * 4 + 1] = v.y;
      Ls[cr][ks + j * 4 + 2] = v.z; Ls[cr][ks + j * 4 + 3] = v.w;
    }
  }
  __syncthreads();
  int kr = t >> 2, cs = (t & 3) * 16;
  unsigned u[8];
  #pragma unroll
  for (int i = 0; i < 8; ++i) {
    float a = Ls[cs + 2 * i][kr] * scale;
    float b = Ls[cs + 2 * i + 1][kr] * scale;
    u[i] = (unsigned)f2bf(a) | ((unsigned)f2bf(b) << 16);
  }
  short* dst = Wt + ((size_t)h * 64 + kr) * C_ + cb * 64 + cs;
  uint4 p0; p0.x = u[0]; p0.y = u[1]; p0.z = u[2]; p0.w = u[3];
  uint4 p1; p1.x = u[4]; p1.y = u[5]; p1.z = u[6]; p1.w = u[7];
  *(uint4*)dst = p0;
  *(uint4*)(dst + 8) = p1;
}

// Mixer weight: plain fp32 -> bf16 (already in B^T form: out@W.T uses W[n][c]).
__global__ __launch_bounds__(256) void wprep_mix_kernel(
    const float* __restrict__ wm, short* __restrict__ wmb) {
  int gid = blockIdx.x * 256 + threadIdx.x;
  float4 v = ((const float4*)wm)[gid];
  uint2 o;
  o.x = (unsigned)f2bf(v.x) | ((unsigned)f2bf(v.y) << 16);
  o.y = (unsigned)f2bf(v.z) | ((unsigned)f2bf(v.w) << 16);
  ((uint2*)wmb)[gid] = o;
}

// ---------------------------------------------------------------------------
// bf16 MFMA GEMM core: C[128x128] tile of A[*,1024] x Bt[*,1024]^T.
// 256 threads = 4 waves (2x2), 16x16x32 MFMA, 4x4 frags/wave, BK=64.
// global_load_lds width-16 staging; XOR-swizzled LDS (conflict-free frags).
// ---------------------------------------------------------------------------
__device__ __forceinline__ void gemm_core(
    const short* __restrict__ A, const short* __restrict__ Bt,
    int arow0, int brow0, short* As, short* Bs, float4v acc[4][4]) {
  int tid = threadIdx.x;
  int wave = tid >> 6, lane = tid & 63;
  int lr = lane >> 3, lc = lane & 7;
  int sc = lc ^ lr;                       // swizzled global chunk for staging
  int wr = wave >> 1, wc = wave & 1;
  int lg = lane >> 4, ll = lane & 15;

  #pragma unroll
  for (int mi = 0; mi < 4; ++mi)
    #pragma unroll
    for (int ni = 0; ni < 4; ++ni) {
      acc[mi][ni][0] = 0.f; acc[mi][ni][1] = 0.f;
      acc[mi][ni][2] = 0.f; acc[mi][ni][3] = 0.f;
    }

  for (int k0 = 0; k0 < C_; k0 += 64) {
    __syncthreads();
    #pragma unroll
    for (int j = 0; j < 4; ++j) {
      int seg = wave * 4 + j;            // 8-row segment of the 128-row tile
      int r = seg * 8 + lr;
      gload_lds16(A + (size_t)(arow0 + r) * C_ + k0 + sc * 8, As + seg * 512);
      gload_lds16(Bt + (size_t)(brow0 + r) * C_ + k0 + sc * 8, Bs + seg * 512);
    }
    __syncthreads();
    #pragma unroll
    for (int kc = 0; kc < 2; ++kc) {
      int cc = kc * 4 + lg;
      short8 af[4], bf[4];
      #pragma unroll
      for (int mi = 0; mi < 4; ++mi) {
        int m = wr * 64 + mi * 16 + ll;
        af[mi] = *(const short8*)&As[m * 64 + ((cc ^ (m & 7)) << 3)];
      }
      #pragma unroll
      for (int ni = 0; ni < 4; ++ni) {
        int n = wc * 64 + ni * 16 + ll;
        bf[ni] = *(const short8*)&Bs[n * 64 + ((cc ^ (n & 7)) << 3)];
      }
      #pragma unroll
      for (int mi = 0; mi < 4; ++mi)
        #pragma unroll
        for (int ni = 0; ni < 4; ++ni)
          acc[mi][ni] = __builtin_amdgcn_mfma_f32_16x16x32_bf16(
              af[mi], bf[ni], acc[mi][ni], 0, 0, 0);
    }
  }
}

// ---------------------------------------------------------------------------
// QKV GEMMs, fused in grid.z: z=0 Q=x1@Wq^T, z=1 K=x2@Wk^T,
// z=2 V^T = Wv x2^T (operand-swapped so stores into [B,H,K,W] coalesce).
// Outputs bf16. grid=(32,8,3).
// ---------------------------------------------------------------------------
__global__ __launch_bounds__(256, 3) void gemm_qkv_kernel(
    const short* __restrict__ x1b, const short* __restrict__ x2b,
    const short* __restrict__ wqt, const short* __restrict__ wkt,
    const short* __restrict__ wvt,
    short* __restrict__ qb, short* __restrict__ kb, short* __restrict__ vtb) {
  __shared__ short As[128 * 64], Bs[128 * 64];
  int z = blockIdx.z;
  const short *A, *Bt;
  int arow0, brow0;
  if (z == 0)      { A = x1b; Bt = wqt; arow0 = blockIdx.x * 128; brow0 = blockIdx.y * 128; }
  else if (z == 1) { A = x2b; Bt = wkt; arow0 = blockIdx.x * 128; brow0 = blockIdx.y * 128; }
  else             { A = wvt; Bt = x2b; arow0 = blockIdx.y * 128; brow0 = blockIdx.x * 128; }

  float4v acc[4][4];
  gemm_core(A, Bt, arow0, brow0, As, Bs, acc);

  int wave = threadIdx.x >> 6, lane = threadIdx.x & 63;
  int wr = wave >> 1, wc = wave & 1, lg = lane >> 4, ll = lane & 15;
  if (z <= 1) {
    short* O = (z == 0) ? qb : kb;
    #pragma unroll
    for (int mi = 0; mi < 4; ++mi)
      #pragma unroll
      for (int ni = 0; ni < 4; ++ni) {
        int n = brow0 + wc * 64 + ni * 16 + ll;       // h*64+k
        int h = n >> 6, kk = n & 63;
        #pragma unroll
        for (int r2 = 0; r2 < 4; ++r2) {
          int m = arow0 + wr * 64 + mi * 16 + lg * 4 + r2;  // seq index
          int b = m >> 11, w = m & (W_ - 1);
          O[((size_t)(b * H_ + h) * W_ + w) * K_ + kk] = (short)f2bf(acc[mi][ni][r2]);
        }
      }
  } else {
    #pragma unroll
    for (int mi = 0; mi < 4; ++mi)
      #pragma unroll
      for (int ni = 0; ni < 4; ++ni) {
        int n = brow0 + wc * 64 + ni * 16 + ll;       // seq index
        int b = n >> 11, w = n & (W_ - 1);
        #pragma unroll
        for (int r2 = 0; r2 < 4; ++r2) {
          int m = arow0 + wr * 64 + mi * 16 + lg * 4 + r2;  // h*64+k
          int h = m >> 6, kk = m & 63;
          vtb[((size_t)(b * H_ + h) * K_ + kk) * W_ + w] = (short)f2bf(acc[mi][ni][r2]);
        }
      }
  }
}

// ---------------------------------------------------------------------------
// Mixer GEMM: out[4096,1024] fp32 = attnb @ wmb^T + bias. grid=(32,8).
// ---------------------------------------------------------------------------
__global__ __launch_bounds__(256, 3) void gemm_mix_kernel(
    const short* __restrict__ attnb, const short* __restrict__ wmb,
    const float* __restrict__ bias, float* __restrict__ out) {
  __shared__ short As[128 * 64], Bs[128 * 64];
  int arow0 = blockIdx.x * 128, brow0 = blockIdx.y * 128;
  float4v acc[4][4];
  gemm_core(attnb, wmb, arow0, brow0, As, Bs, acc);

  int wave = threadIdx.x >> 6, lane = threadIdx.x & 63;
  int wr = wave >> 1, wc = wave & 1, lg = lane >> 4, ll = lane & 15;
  #pragma unroll
  for (int mi = 0; mi < 4; ++mi)
    #pragma unroll
    for (int ni = 0; ni < 4; ++ni) {
      int n = brow0 + wc * 64 + ni * 16 + ll;
      float bv = bias[n];
      #pragma unroll
      for (int r2 = 0; r2 < 4; ++r2) {
        int m = arow0 + wr * 64 + mi * 16 + lg * 4 + r2;
        out[(size_t)m * C_ + n] = acc[mi][ni][r2] + bv;
      }
    }
}

// ---------------------------------------------------------------------------
// Causal flash attention partial pass: transposed-S scheme + key-split.
// grid=(64, B*H, SEG_), block=128 (2 waves x 16 queries). Wave (qb,seg)
// covers key tiles [seg*8, min(seg*8+8, diag+1)). Per 64-key tile:
//   S^T = K·Q^T (C-layout col = query -> lane-local softmax, 2 shuffles),
//   P^T C-layout regs feed mfma_16x16x16 directly: O^T += V^T·P^T.
// Writes partials: m,l fp32 + unnormalized O^T bf16 (combined next pass).
// VGPR kept <=64 -> 8 waves/SIMD; 16384 waves total for latency hiding.
// ---------------------------------------------------------------------------
__global__ __launch_bounds__(128) void attn_partial_kernel(
    const short* __restrict__ q, const short* __restrict__ k,
    const short* __restrict__ vt,
    float* __restrict__ pm, float* __restrict__ pl, short* __restrict__ pacc) {
  int bh = blockIdx.y;
  int seg = blockIdx.z;
  int qb = 63 - (int)blockIdx.x;                  // heavy q-tiles first
  int wave = threadIdx.x >> 6;                    // 0..1
  int lane = threadIdx.x & 63;
  int lg = lane >> 4, ll = lane & 15;
  int q0 = qb * 32 + wave * 16;                   // wave's query base
  int myq = q0 + ll;                              // this lane's query

  const short* qp = q + (size_t)bh * W_ * K_;
  const short* kp = k + (size_t)bh * W_ * K_;
  const short* vb = vt + (size_t)bh * K_ * W_;

  int dt = qb >> 1;                               // diagonal 64-key tile
  int ktlo = seg * TPS;
  int kthi = min(seg * TPS + TPS, dt + 1);

  float4v o[4];
  #pragma unroll
  for (int ct = 0; ct < 4; ++ct) { o[ct][0] = 0.f; o[ct][1] = 0.f; o[ct][2] = 0.f; o[ct][3] = 0.f; }
  float m_i = -INFINITY, l_i = 0.0f;

  if (ktlo < kthi) {
    // Q as B-operand (Q^T): lane holds Q[myq][kc*32 + lg*8 + j]
    short8 bq[2];
    #pragma unroll
    for (int kc = 0; kc < 2; ++kc)
      bq[kc] = *(const short8*)(qp + (size_t)myq * K_ + kc * 32 + lg * 8);

    for (int kt = ktlo; kt < kthi; ++kt) {
      const short* kbase = kp + (size_t)kt * 64 * K_;
      // ---- S^T tiles: st[mt] holds S[query=myq][key=kt*64+mt*16+lg*4+r] ----
      float4v st[4];
      #pragma unroll
      for (int mt = 0; mt < 4; ++mt) {
        st[mt][0] = 0.f; st[mt][1] = 0.f; st[mt][2] = 0.f; st[mt][3] = 0.f;
        #pragma unroll
        for (int kc = 0; kc < 2; ++kc) {
          short8 ak = *(const short8*)(kbase + (size_t)(mt * 16 + ll) * K_ + kc * 32 + lg * 8);
          st[mt] = __builtin_amdgcn_mfma_f32_16x16x32_bf16(ak, bq[kc], st[mt], 0, 0, 0);
        }
      }
      // ---- V^T A-frags (independent: issue early to cover softmax) ----
      short4v va[4][4];
      #pragma unroll
      for (int ct = 0; ct < 4; ++ct)
        #pragma unroll
        for (int t = 0; t < 4; ++t)
          va[ct][t] = *(const short4v*)(vb + (size_t)(ct * 16 + ll) * W_ +
                                        kt * 64 + t * 16 + lg * 4);
      // ---- causal mask (diagonal tile only) ----
      if (kt == dt) {
        #pragma unroll
        for (int mt = 0; mt < 4; ++mt)
          #pragma unroll
          for (int r = 0; r < 4; ++r) {
            int key = kt * 64 + mt * 16 + lg * 4 + r;
            if (key > myq) st[mt][r] = -INFINITY;
          }
      }
      // ---- lane-local online softmax, tree reductions ----
      float mx[4];
      #pragma unroll
      for (int mt = 0; mt < 4; ++mt)
        mx[mt] = fmaxf(fmaxf(st[mt][0], st[mt][1]), fmaxf(st[mt][2], st[mt][3]));
      float tmax = fmaxf(fmaxf(mx[0], mx[1]), fmaxf(mx[2], mx[3]));
      tmax = fmaxf(tmax, __shfl_xor(tmax, 16, 64));
      tmax = fmaxf(tmax, __shfl_xor(tmax, 32, 64));
      float nm = fmaxf(m_i, tmax);
      float alpha = __expf(m_i - nm);   // first iter: exp(-inf)=0
      m_i = nm;
      float p[4][4];
      float pssub[4];
      #pragma unroll
      for (int mt = 0; mt < 4; ++mt) {
        #pragma unroll
        for (int r = 0; r < 4; ++r) p[mt][r] = __expf(st[mt][r] - nm);
        pssub[mt] = (p[mt][0] + p[mt][1]) + (p[mt][2] + p[mt][3]);
      }
      float ps = (pssub[0] + pssub[1]) + (pssub[2] + pssub[3]);
      ps += __shfl_xor(ps, 16, 64);
      ps += __shfl_xor(ps, 32, 64);
      l_i = l_i * alpha + ps;
      #pragma unroll
      for (int ct = 0; ct < 4; ++ct) {
        o[ct][0] *= alpha; o[ct][1] *= alpha; o[ct][2] *= alpha; o[ct][3] *= alpha;
      }
      // ---- P^T B-frags (bf16) straight from registers ----
      short4v pb[4];
      #pragma unroll
      for (int t = 0; t < 4; ++t) {
        pb[t][0] = (short)f2bf(p[t][0]); pb[t][1] = (short)f2bf(p[t][1]);
        pb[t][2] = (short)f2bf(p[t][2]); pb[t][3] = (short)f2bf(p[t][3]);
      }
      // ---- O^T += V^T · P^T ----
      #pragma unroll
      for (int ct = 0; ct < 4; ++ct)
        #pragma unroll
        for (int t = 0; t < 4; ++t)
          o[ct] = mfma_16x16x16_bf16(va[ct][t], pb[t], o[ct]);
    }
  }

  // ---- write partials (always, including empty waves) ----
  size_t pbase = ((size_t)(bh * SEG_ + seg)) * W_ + q0;
  if (lg == 0) {                       // lanes 0..15: contiguous fp32 stores
    pm[pbase + ll] = m_i;
    pl[pbase + ll] = l_i;
  }
  short* pa = pacc + ((pbase + ll) << 6);  // [.. q ..]*64 + chan
  #pragma unroll
  for (int ct = 0; ct < 4; ++ct) {
    uint2 pk;
    pk.x = (unsigned)f2bf(o[ct][0]) | ((unsigned)f2bf(o[ct][1]) << 16);
    pk.y = (unsigned)f2bf(o[ct][2]) | ((unsigned)f2bf(o[ct][3]) << 16);
    *(uint2*)(pa + ct * 16 + lg * 4) = pk;
  }
}

// ---------------------------------------------------------------------------
// Combine key-split partials -> attnb bf16 [B,W,C].
// One thread per (bh, q, chan); coalesced pacc reads / attnb writes.
// ---------------------------------------------------------------------------
__global__ __launch_bounds__(256) void attn_combine_kernel(
    const float* __restrict__ pm, const float* __restrict__ pl,
    const short* __restrict__ pacc, short* __restrict__ attnb) {
  int gid = blockIdx.x * 256 + threadIdx.x;
  int c = gid & 63;
  int qq = (gid >> 6) & (W_ - 1);
  int bh = gid >> 17;
  size_t base = (size_t)bh * SEG_ * W_ + qq;

  float ms[SEG_], ls[SEG_];
  float M = -INFINITY;
  #pragma unroll
  for (int s = 0; s < SEG_; ++s) {
    ms[s] = pm[base + (size_t)s * W_];
    ls[s] = pl[base + (size_t)s * W_];
    M = fmaxf(M, ms[s]);
  }
  float L = 0.f, ov = 0.f;
  #pragma unroll
  for (int s = 0; s < SEG_; ++s) {
    float sc = __expf(ms[s] - M);      // M finite (seg0 never empty)
    L += ls[s] * sc;
    ov += sc * bf2f(pacc[((base + (size_t)s * W_) << 6) + c]);
  }
  int b = bh >> 4, h = bh & 15;
  attnb[((size_t)(b * W_ + qq)) * C_ + h * K_ + c] = (short)f2bf(ov / L);
}

// ---------------------------------------------------------------------------
extern "C" void kernel_launch(void* const* d_in, const int* in_sizes, int n_in,
                              void* d_out, int out_size, void* d_ws, size_t ws_size,
                              hipStream_t stream) {
  const float* seq1  = (const float*)d_in[0];
  const float* seq2  = (const float*)d_in[1];
  const float* gamma = (const float*)d_in[2];
  const float* beta  = (const float*)d_in[3];
  const float* qp    = (const float*)d_in[4];
  const float* kp    = (const float*)d_in[5];
  const float* vp    = (const float*)d_in[6];
  const float* wm    = (const float*)d_in[7];
  const float* mb    = (const float*)d_in[8];
  float* out = (float*)d_out;

  char* ws = (char*)d_ws;
  const size_t NROW = (size_t)B_ * W_;               // 4096
  const size_t XB = NROW * C_ * sizeof(short);       // 8 MB bf16 activation buf
  const size_t WB = (size_t)C_ * C_ * sizeof(short); // 2 MB bf16 weight buf
  const size_t NP = (size_t)B_ * H_ * SEG_ * W_;     // 262144 partial slots
  short* x1b = (short*)(ws);
  short* x2b = (short*)(ws + XB);
  short* qb  = (short*)(ws + 2 * XB);
  short* kb  = (short*)(ws + 3 * XB);
  short* vtb = (short*)(ws + 4 * XB);
  short* wqt = (short*)(ws + 5 * XB);
  short* wkt = (short*)(ws + 5 * XB + WB);
  short* wvt = (short*)(ws + 5 * XB + 2 * WB);
  short* wmb = (short*)(ws + 5 * XB + 3 * WB);
  short* attnb = (short*)(ws + 5 * XB + 4 * WB);
  char* pbase_ws = ws + 6 * XB + 4 * WB;
  float* pm = (float*)(pbase_ws);
  float* pl = (float*)(pbase_ws + NP * sizeof(float));
  short* pacc = (short*)(pbase_ws + 2 * NP * sizeof(float));  // NP*64 bf16 = 33.5 MB

  wprep_proj_kernel<<<dim3(C_ / 64, H_, 3), dim3(256), 0, stream>>>(
      qp, kp, vp, wqt, wkt, wvt);
  wprep_mix_kernel<<<dim3(C_ * C_ / 1024), dim3(256), 0, stream>>>(wm, wmb);
  ln_kernel<<<dim3(2 * (unsigned)NROW), dim3(256), 0, stream>>>(
      seq1, seq2, gamma, beta, x1b, x2b);
  gemm_qkv_kernel<<<dim3(32, 8, 3), dim3(256), 0, stream>>>(
      x1b, x2b, wqt, wkt, wvt, qb, kb, vtb);
  attn_partial_kernel<<<dim3(64, B_ * H_, SEG_), dim3(128), 0, stream>>>(
      qb, kb, vtb, pm, pl, pacc);
  attn_combine_kernel<<<dim3((unsigned)(NROW * H_ * K_ / 256)), dim3(256), 0, stream>>>(
      pm, pl, pacc, attnb);
  gemm_mix_kernel<<<dim3(32, 8), dim3(256), 0, stream>>>(attnb, wmb, mb, out);
}

// Round 7
// 303.072 us; speedup vs baseline: 1.6117x; 1.4694x over previous
//
#include <hip/hip_runtime.h>
#include <math.h>

#define B_ 2
#define W_ 2048
#define C_ 1024
#define H_ 16
#define K_ 64
#define LN_EPS 1e-5f

typedef __attribute__((ext_vector_type(8))) short short8;   // 8 bf16 (4 VGPRs)
typedef __attribute__((ext_vector_type(4))) float float4v;  // MFMA C/D frag

__device__ inline unsigned short f2bf(float f) {  // RNE float->bf16
  unsigned u = __float_as_uint(f);
  u += 0x7fffu + ((u >> 16) & 1u);
  return (unsigned short)(u >> 16);
}

__device__ __forceinline__ void gload_lds16(const short* g, short* l) {
  __builtin_amdgcn_global_load_lds(
      (const __attribute__((address_space(1))) void*)g,
      (__attribute__((address_space(3))) void*)l, 16, 0, 0);
}

// ---------------------------------------------------------------------------
// Block-wide sum over 256 threads (4 waves of 64)
// ---------------------------------------------------------------------------
__device__ inline float block_sum(float val) {
  __shared__ float sb[4];
  #pragma unroll
  for (int o = 32; o > 0; o >>= 1) val += __shfl_down(val, o, 64);
  int lane = threadIdx.x & 63, wid = threadIdx.x >> 6;
  if (lane == 0) sb[wid] = val;
  __syncthreads();
  float r = sb[0] + sb[1] + sb[2] + sb[3];
  __syncthreads();
  return r;
}

// ---------------------------------------------------------------------------
// LayerNorm -> bf16 output. One block per row; handles both seq1 and seq2.
// ---------------------------------------------------------------------------
__global__ __launch_bounds__(256) void ln_kernel(
    const float* __restrict__ seq1, const float* __restrict__ seq2,
    const float* __restrict__ gamma, const float* __restrict__ beta,
    short* __restrict__ x1b, short* __restrict__ x2b) {
  int row = blockIdx.x;
  const int nrows = B_ * W_;
  bool first = row < nrows;
  const float* src = first ? seq1 : seq2;
  short* dst = first ? x1b : x2b;
  int r = first ? row : row - nrows;

  const float4* p = (const float4*)(src + (size_t)r * C_);
  float4 v = p[threadIdx.x];
  float mean = block_sum(v.x + v.y + v.z + v.w) * (1.0f / C_);
  float dx = v.x - mean, dy = v.y - mean, dz = v.z - mean, dw = v.w - mean;
  float var = block_sum(dx * dx + dy * dy + dz * dz + dw * dw) * (1.0f / C_);
  float rstd = rsqrtf(var + LN_EPS);

  float4 g = ((const float4*)gamma)[threadIdx.x];
  float4 b = ((const float4*)beta)[threadIdx.x];
  uint2 o;
  o.x = (unsigned)f2bf(dx * rstd * g.x + b.x) |
        ((unsigned)f2bf(dy * rstd * g.y + b.y) << 16);
  o.y = (unsigned)f2bf(dz * rstd * g.z + b.z) |
        ((unsigned)f2bf(dw * rstd * g.w + b.w) << 16);
  ((uint2*)(dst + (size_t)r * C_))[threadIdx.x] = o;
}

// ---------------------------------------------------------------------------
// Weight prep: proj [H,C,K] fp32 -> B^T bf16 [H*K rows][C cols], q scaled by
// 1/sqrt(K) (exact pow2). grid=(C/64, H, 3), block=256, LDS transpose.
// ---------------------------------------------------------------------------
__global__ __launch_bounds__(256) void wprep_proj_kernel(
    const float* __restrict__ qp, const float* __restrict__ kp,
    const float* __restrict__ vp,
    short* __restrict__ wqt, short* __restrict__ wkt, short* __restrict__ wvt) {
  int cb = blockIdx.x, h = blockIdx.y, which = blockIdx.z;
  const float* P = (which == 0 ? qp : (which == 1 ? kp : vp)) + (size_t)h * C_ * K_;
  short* Wt = (which == 0 ? wqt : (which == 1 ? wkt : wvt));
  float scale = (which == 0) ? 0.125f : 1.0f;

  __shared__ float Ls[64][65];
  int t = threadIdx.x;
  {
    int cr = t >> 2, ks = (t & 3) * 16;
    const float* src = P + (size_t)(cb * 64 + cr) * K_ + ks;
    #pragma unroll
    for (int j = 0; j < 4; ++j) {
      float4 v = *(const float4*)(src + j * 4);
      Ls[cr][ks + j * 4 + 0] = v.x; Ls[cr][ks + j * 4 + 1] = v.y;
      Ls[cr][ks + j * 4 + 2] = v.z; Ls[cr][ks + j * 4 + 3] = v.w;
    }
  }
  __syncthreads();
  int kr = t >> 2, cs = (t & 3) * 16;
  unsigned u[8];
  #pragma unroll
  for (int i = 0; i < 8; ++i) {
    float a = Ls[cs + 2 * i][kr] * scale;
    float b = Ls[cs + 2 * i + 1][kr] * scale;
    u[i] = (unsigned)f2bf(a) | ((unsigned)f2bf(b) << 16);
  }
  short* dst = Wt + ((size_t)h * 64 + kr) * C_ + cb * 64 + cs;
  uint4 p0; p0.x = u[0]; p0.y = u[1]; p0.z = u[2]; p0.w = u[3];
  uint4 p1; p1.x = u[4]; p1.y = u[5]; p1.z = u[6]; p1.w = u[7];
  *(uint4*)dst = p0;
  *(uint4*)(dst + 8) = p1;
}

// Mixer weight: plain fp32 -> bf16 (already in B^T form: out@W.T uses W[n][c]).
__global__ __launch_bounds__(256) void wprep_mix_kernel(
    const float* __restrict__ wm, short* __restrict__ wmb) {
  int gid = blockIdx.x * 256 + threadIdx.x;
  float4 v = ((const float4*)wm)[gid];
  uint2 o;
  o.x = (unsigned)f2bf(v.x) | ((unsigned)f2bf(v.y) << 16);
  o.y = (unsigned)f2bf(v.z) | ((unsigned)f2bf(v.w) << 16);
  ((uint2*)wmb)[gid] = o;
}

// ---------------------------------------------------------------------------
// bf16 MFMA GEMM core: C[128x128] tile of A[*,1024] x Bt[*,1024]^T.
// 256 threads = 4 waves (2x2), 16x16x32 MFMA, 4x4 frags/wave, BK=64.
// global_load_lds width-16 staging; XOR-swizzled LDS (conflict-free frags).
// ---------------------------------------------------------------------------
__device__ __forceinline__ void gemm_core(
    const short* __restrict__ A, const short* __restrict__ Bt,
    int arow0, int brow0, short* As, short* Bs, float4v acc[4][4]) {
  int tid = threadIdx.x;
  int wave = tid >> 6, lane = tid & 63;
  int lr = lane >> 3, lc = lane & 7;
  int sc = lc ^ lr;                       // swizzled global chunk for staging
  int wr = wave >> 1, wc = wave & 1;
  int lg = lane >> 4, ll = lane & 15;

  #pragma unroll
  for (int mi = 0; mi < 4; ++mi)
    #pragma unroll
    for (int ni = 0; ni < 4; ++ni) {
      acc[mi][ni][0] = 0.f; acc[mi][ni][1] = 0.f;
      acc[mi][ni][2] = 0.f; acc[mi][ni][3] = 0.f;
    }

  for (int k0 = 0; k0 < C_; k0 += 64) {
    __syncthreads();
    #pragma unroll
    for (int j = 0; j < 4; ++j) {
      int seg = wave * 4 + j;            // 8-row segment of the 128-row tile
      int r = seg * 8 + lr;
      gload_lds16(A + (size_t)(arow0 + r) * C_ + k0 + sc * 8, As + seg * 512);
      gload_lds16(Bt + (size_t)(brow0 + r) * C_ + k0 + sc * 8, Bs + seg * 512);
    }
    __syncthreads();
    #pragma unroll
    for (int kc = 0; kc < 2; ++kc) {
      int cc = kc * 4 + lg;
      short8 af[4], bf[4];
      #pragma unroll
      for (int mi = 0; mi < 4; ++mi) {
        int m = wr * 64 + mi * 16 + ll;
        af[mi] = *(const short8*)&As[m * 64 + ((cc ^ (m & 7)) << 3)];
      }
      #pragma unroll
      for (int ni = 0; ni < 4; ++ni) {
        int n = wc * 64 + ni * 16 + ll;
        bf[ni] = *(const short8*)&Bs[n * 64 + ((cc ^ (n & 7)) << 3)];
      }
      #pragma unroll
      for (int mi = 0; mi < 4; ++mi)
        #pragma unroll
        for (int ni = 0; ni < 4; ++ni)
          acc[mi][ni] = __builtin_amdgcn_mfma_f32_16x16x32_bf16(
              af[mi], bf[ni], acc[mi][ni], 0, 0, 0);
    }
  }
}

// ---------------------------------------------------------------------------
// QKV GEMMs, fused in grid.z: z=0 Q=x1@Wq^T, z=1 K=x2@Wk^T,
// z=2 V^T = Wv x2^T (operand-swapped so stores into [B,H,K,W] coalesce).
// Outputs bf16. grid=(32,8,3).
// ---------------------------------------------------------------------------
__global__ __launch_bounds__(256, 3) void gemm_qkv_kernel(
    const short* __restrict__ x1b, const short* __restrict__ x2b,
    const short* __restrict__ wqt, const short* __restrict__ wkt,
    const short* __restrict__ wvt,
    short* __restrict__ qb, short* __restrict__ kb, short* __restrict__ vtb) {
  __shared__ short As[128 * 64], Bs[128 * 64];
  int z = blockIdx.z;
  const short *A, *Bt;
  int arow0, brow0;
  if (z == 0)      { A = x1b; Bt = wqt; arow0 = blockIdx.x * 128; brow0 = blockIdx.y * 128; }
  else if (z == 1) { A = x2b; Bt = wkt; arow0 = blockIdx.x * 128; brow0 = blockIdx.y * 128; }
  else             { A = wvt; Bt = x2b; arow0 = blockIdx.y * 128; brow0 = blockIdx.x * 128; }

  float4v acc[4][4];
  gemm_core(A, Bt, arow0, brow0, As, Bs, acc);

  int wave = threadIdx.x >> 6, lane = threadIdx.x & 63;
  int wr = wave >> 1, wc = wave & 1, lg = lane >> 4, ll = lane & 15;
  if (z <= 1) {
    short* O = (z == 0) ? qb : kb;
    #pragma unroll
    for (int mi = 0; mi < 4; ++mi)
      #pragma unroll
      for (int ni = 0; ni < 4; ++ni) {
        int n = brow0 + wc * 64 + ni * 16 + ll;       // h*64+k
        int h = n >> 6, kk = n & 63;
        #pragma unroll
        for (int r2 = 0; r2 < 4; ++r2) {
          int m = arow0 + wr * 64 + mi * 16 + lg * 4 + r2;  // seq index
          int b = m >> 11, w = m & (W_ - 1);
          O[((size_t)(b * H_ + h) * W_ + w) * K_ + kk] = (short)f2bf(acc[mi][ni][r2]);
        }
      }
  } else {
    #pragma unroll
    for (int mi = 0; mi < 4; ++mi)
      #pragma unroll
      for (int ni = 0; ni < 4; ++ni) {
        int n = brow0 + wc * 64 + ni * 16 + ll;       // seq index
        int b = n >> 11, w = n & (W_ - 1);
        #pragma unroll
        for (int r2 = 0; r2 < 4; ++r2) {
          int m = arow0 + wr * 64 + mi * 16 + lg * 4 + r2;  // h*64+k
          int h = m >> 6, kk = m & 63;
          vtb[((size_t)(b * H_ + h) * K_ + kk) * W_ + w] = (short)f2bf(acc[mi][ni][r2]);
        }
      }
  }
}

// ---------------------------------------------------------------------------
// Mixer GEMM: out[4096,1024] fp32 = attnb @ wmb^T + bias. grid=(32,8).
// ---------------------------------------------------------------------------
__global__ __launch_bounds__(256, 3) void gemm_mix_kernel(
    const short* __restrict__ attnb, const short* __restrict__ wmb,
    const float* __restrict__ bias, float* __restrict__ out) {
  __shared__ short As[128 * 64], Bs[128 * 64];
  int arow0 = blockIdx.x * 128, brow0 = blockIdx.y * 128;
  float4v acc[4][4];
  gemm_core(attnb, wmb, arow0, brow0, As, Bs, acc);

  int wave = threadIdx.x >> 6, lane = threadIdx.x & 63;
  int wr = wave >> 1, wc = wave & 1, lg = lane >> 4, ll = lane & 15;
  #pragma unroll
  for (int mi = 0; mi < 4; ++mi)
    #pragma unroll
    for (int ni = 0; ni < 4; ++ni) {
      int n = brow0 + wc * 64 + ni * 16 + ll;
      float bv = bias[n];
      #pragma unroll
      for (int r2 = 0; r2 < 4; ++r2) {
        int m = arow0 + wr * 64 + mi * 16 + lg * 4 + r2;
        out[(size_t)m * C_ + n] = acc[mi][ni][r2] + bv;
      }
    }
}

// ---------------------------------------------------------------------------
// Causal flash attention on the m97 GEMM skeleton. grid=(16, B*H), block=256
// (4 waves). Block = 128 q-rows (wave w -> rows w*16 and 64+w*16).
// Per 64-key tile: K[64x64] and V^T[64x64] staged via coalesced
// global_load_lds (XOR-swizzled on the global side), then:
//   S = Q.K^T (16 MFMA from ds_read_b128 frags), R4-style online softmax,
//   P via wave-private LDS roundtrip (stride 76: conflict-free),
//   O += P.V (16 MFMA from staged V^T frags).
// ---------------------------------------------------------------------------
__global__ __launch_bounds__(256, 3) void attn_mfma_kernel(
    const short* __restrict__ q, const short* __restrict__ k,
    const short* __restrict__ vt, short* __restrict__ out) {
  int bh = blockIdx.y;
  int b = bh >> 4, h = bh & 15;
  int qt = 15 - (int)blockIdx.x;          // heavy q-tiles first
  int wave = threadIdx.x >> 6;
  int lane = threadIdx.x & 63;
  int lg = lane >> 4, ll = lane & 15;

  __shared__ short Ks[64 * 64];           // [key][chan], swizzled chunks
  __shared__ short Vs[64 * 64];           // [chan][key], swizzled chunks
  __shared__ short Ps[4][16 * 76];        // per-wave P buffer

  const short* qp = q + (size_t)bh * W_ * K_;
  const short* kp = k + (size_t)bh * W_ * K_;
  const short* vb = vt + (size_t)bh * K_ * W_;

  // Q A-frags: mi in {0,1} -> rows qt*128 + mi*64 + wave*16 + ll
  short8 aq[2][2];
  #pragma unroll
  for (int mi = 0; mi < 2; ++mi) {
    int qrow = qt * 128 + mi * 64 + wave * 16 + ll;
    #pragma unroll
    for (int kc = 0; kc < 2; ++kc)
      aq[mi][kc] = *(const short8*)(qp + (size_t)qrow * K_ + kc * 32 + lg * 8);
  }

  float4v o[2][4];
  #pragma unroll
  for (int mi = 0; mi < 2; ++mi)
    #pragma unroll
    for (int ct = 0; ct < 4; ++ct) {
      o[mi][ct][0] = 0.f; o[mi][ct][1] = 0.f; o[mi][ct][2] = 0.f; o[mi][ct][3] = 0.f;
    }
  float m4[2][4], l4[2][4];
  #pragma unroll
  for (int mi = 0; mi < 2; ++mi)
    #pragma unroll
    for (int r = 0; r < 4; ++r) { m4[mi][r] = -INFINITY; l4[mi][r] = 0.f; }

  int nkt = 2 * qt + 2;                   // key tiles covering keys <= qt*128+127
  for (int kt = 0; kt < nkt; ++kt) {
    __syncthreads();
    {  // ---- stage K tile + V^T tile (coalesced, global-side swizzle) ----
      const short* kbase = kp + (size_t)kt * 64 * K_;
      const short* vbase = vb + kt * 64;
      #pragma unroll
      for (int j = 0; j < 2; ++j) {
        int s = j * 256 + threadIdx.x;    // 512 16B-chunks per 8KB tile
        int m = s >> 3, c7 = s & 7;
        int gc = c7 ^ (m & 7);
        gload_lds16(kbase + (size_t)m * K_ + gc * 8, Ks + s * 8);
        gload_lds16(vbase + (size_t)m * W_ + gc * 8, Vs + s * 8);
      }
    }
    __syncthreads();

    // ---- S = Q.K^T for both m-frags ----
    float4v st[2][4];
    #pragma unroll
    for (int mi = 0; mi < 2; ++mi)
      #pragma unroll
      for (int nt = 0; nt < 4; ++nt) {
        st[mi][nt][0] = 0.f; st[mi][nt][1] = 0.f;
        st[mi][nt][2] = 0.f; st[mi][nt][3] = 0.f;
      }
    #pragma unroll
    for (int nt = 0; nt < 4; ++nt) {
      int n = nt * 16 + ll;
      #pragma unroll
      for (int kc = 0; kc < 2; ++kc) {
        int cc = kc * 4 + lg;
        short8 bk = *(const short8*)&Ks[n * 64 + ((cc ^ (n & 7)) << 3)];
        st[0][nt] = __builtin_amdgcn_mfma_f32_16x16x32_bf16(aq[0][kc], bk, st[0][nt], 0, 0, 0);
        st[1][nt] = __builtin_amdgcn_mfma_f32_16x16x32_bf16(aq[1][kc], bk, st[1][nt], 0, 0, 0);
      }
    }
    // ---- V^T B-frags (shared across mi) ----
    short8 bv[4][2];
    #pragma unroll
    for (int ct = 0; ct < 4; ++ct) {
      int c = ct * 16 + ll;
      #pragma unroll
      for (int kc = 0; kc < 2; ++kc) {
        int cc = kc * 4 + lg;
        bv[ct][kc] = *(const short8*)&Vs[c * 64 + ((cc ^ (c & 7)) << 3)];
      }
    }

    bool diag = (kt >= 2 * qt);
    #pragma unroll
    for (int mi = 0; mi < 2; ++mi) {
      float sv[4][4];
      #pragma unroll
      for (int nt = 0; nt < 4; ++nt)
        #pragma unroll
        for (int r = 0; r < 4; ++r) sv[nt][r] = st[mi][nt][r];
      if (diag) {
        int rowb = qt * 128 + mi * 64 + wave * 16 + lg * 4;
        #pragma unroll
        for (int nt = 0; nt < 4; ++nt) {
          int key = kt * 64 + nt * 16 + ll;
          #pragma unroll
          for (int r = 0; r < 4; ++r)
            if (key > rowb + r) sv[nt][r] = -INFINITY;
        }
      }
      // ---- online softmax: stats per row (lg*4+r), reduce over ll lanes ----
      float pv[4][4];
      #pragma unroll
      for (int r = 0; r < 4; ++r) {
        float x = fmaxf(fmaxf(sv[0][r], sv[1][r]), fmaxf(sv[2][r], sv[3][r]));
        x = fmaxf(x, __shfl_xor(x, 1, 64));
        x = fmaxf(x, __shfl_xor(x, 2, 64));
        x = fmaxf(x, __shfl_xor(x, 4, 64));
        x = fmaxf(x, __shfl_xor(x, 8, 64));
        float nm = fmaxf(m4[mi][r], x);
        float al = __expf(m4[mi][r] - nm);  // first tile: exp(-inf)=0
        m4[mi][r] = nm;
        float ps = 0.f;
        #pragma unroll
        for (int nt = 0; nt < 4; ++nt) {
          float e = __expf(sv[nt][r] - nm);
          pv[nt][r] = e;
          ps += e;
        }
        ps += __shfl_xor(ps, 1, 64);
        ps += __shfl_xor(ps, 2, 64);
        ps += __shfl_xor(ps, 4, 64);
        ps += __shfl_xor(ps, 8, 64);
        l4[mi][r] = l4[mi][r] * al + ps;
        #pragma unroll
        for (int ct = 0; ct < 4; ++ct) o[mi][ct][r] *= al;
      }
      // ---- P (C-layout) -> bf16 -> wave-private LDS -> A-layout ----
      short* myP = &Ps[wave][0];
      #pragma unroll
      for (int nt = 0; nt < 4; ++nt)
        #pragma unroll
        for (int r = 0; r < 4; ++r)
          myP[(lg * 4 + r) * 76 + nt * 16 + ll] = (short)f2bf(pv[nt][r]);
      __builtin_amdgcn_s_waitcnt(0xC07F);  // lgkmcnt(0)
      short8 ap[2];
      ap[0] = *(const short8*)(myP + ll * 76 + lg * 8);
      ap[1] = *(const short8*)(myP + ll * 76 + 32 + lg * 8);
      // ---- O += P.V ----
      #pragma unroll
      for (int ct = 0; ct < 4; ++ct) {
        o[mi][ct] = __builtin_amdgcn_mfma_f32_16x16x32_bf16(ap[0], bv[ct][0], o[mi][ct], 0, 0, 0);
        o[mi][ct] = __builtin_amdgcn_mfma_f32_16x16x32_bf16(ap[1], bv[ct][1], o[mi][ct], 0, 0, 0);
      }
    }
  }

  // ---- epilogue: normalize, write bf16 [B,W,C] ----
  #pragma unroll
  for (int mi = 0; mi < 2; ++mi) {
    float inv[4];
    #pragma unroll
    for (int r = 0; r < 4; ++r) inv[r] = 1.0f / l4[mi][r];
    #pragma unroll
    for (int ct = 0; ct < 4; ++ct)
      #pragma unroll
      for (int r = 0; r < 4; ++r) {
        int row = qt * 128 + mi * 64 + wave * 16 + lg * 4 + r;
        out[((size_t)(b * W_ + row)) * C_ + h * K_ + ct * 16 + ll] =
            (short)f2bf(o[mi][ct][r] * inv[r]);
      }
  }
}

// ---------------------------------------------------------------------------
extern "C" void kernel_launch(void* const* d_in, const int* in_sizes, int n_in,
                              void* d_out, int out_size, void* d_ws, size_t ws_size,
                              hipStream_t stream) {
  const float* seq1  = (const float*)d_in[0];
  const float* seq2  = (const float*)d_in[1];
  const float* gamma = (const float*)d_in[2];
  const float* beta  = (const float*)d_in[3];
  const float* qp    = (const float*)d_in[4];
  const float* kp    = (const float*)d_in[5];
  const float* vp    = (const float*)d_in[6];
  const float* wm    = (const float*)d_in[7];
  const float* mb    = (const float*)d_in[8];
  float* out = (float*)d_out;

  char* ws = (char*)d_ws;
  const size_t NROW = (size_t)B_ * W_;               // 4096
  const size_t XB = NROW * C_ * sizeof(short);       // 8 MB bf16 activation buf
  const size_t WB = (size_t)C_ * C_ * sizeof(short); // 2 MB bf16 weight buf
  short* x1b = (short*)(ws);
  short* x2b = (short*)(ws + XB);
  short* qb  = (short*)(ws + 2 * XB);
  short* kb  = (short*)(ws + 3 * XB);
  short* vtb = (short*)(ws + 4 * XB);
  short* wqt = (short*)(ws + 5 * XB);
  short* wkt = (short*)(ws + 5 * XB + WB);
  short* wvt = (short*)(ws + 5 * XB + 2 * WB);
  short* wmb = (short*)(ws + 5 * XB + 3 * WB);
  short* attnb = (short*)(ws + 5 * XB + 4 * WB);

  wprep_proj_kernel<<<dim3(C_ / 64, H_, 3), dim3(256), 0, stream>>>(
      qp, kp, vp, wqt, wkt, wvt);
  wprep_mix_kernel<<<dim3(C_ * C_ / 1024), dim3(256), 0, stream>>>(wm, wmb);
  ln_kernel<<<dim3(2 * (unsigned)NROW), dim3(256), 0, stream>>>(
      seq1, seq2, gamma, beta, x1b, x2b);
  gemm_qkv_kernel<<<dim3(32, 8, 3), dim3(256), 0, stream>>>(
      x1b, x2b, wqt, wkt, wvt, qb, kb, vtb);
  attn_mfma_kernel<<<dim3(16, B_ * H_), dim3(256), 0, stream>>>(
      qb, kb, vtb, attnb);
  gemm_mix_kernel<<<dim3(32, 8), dim3(256), 0, stream>>>(attnb, wmb, mb, out);
}

// Round 8
// 230.874 us; speedup vs baseline: 2.1157x; 1.3127x over previous
//
#include <hip/hip_runtime.h>
#include <math.h>

#define B_ 2
#define W_ 2048
#define C_ 1024
#define H_ 16
#define K_ 64
#define LN_EPS 1e-5f

typedef __attribute__((ext_vector_type(8))) short short8;   // 8 bf16 (4 VGPRs)
typedef __attribute__((ext_vector_type(4))) float float4v;  // MFMA C/D frag

__device__ inline unsigned short f2bf(float f) {  // RNE float->bf16
  unsigned u = __float_as_uint(f);
  u += 0x7fffu + ((u >> 16) & 1u);
  return (unsigned short)(u >> 16);
}

__device__ __forceinline__ void gload_lds16(const short* g, short* l) {
  __builtin_amdgcn_global_load_lds(
      (const __attribute__((address_space(1))) void*)g,
      (__attribute__((address_space(3))) void*)l, 16, 0, 0);
}

// ---------------------------------------------------------------------------
// Block-wide sum over 256 threads (4 waves of 64)
// ---------------------------------------------------------------------------
__device__ inline float block_sum(float val) {
  __shared__ float sb[4];
  #pragma unroll
  for (int o = 32; o > 0; o >>= 1) val += __shfl_down(val, o, 64);
  int lane = threadIdx.x & 63, wid = threadIdx.x >> 6;
  if (lane == 0) sb[wid] = val;
  __syncthreads();
  float r = sb[0] + sb[1] + sb[2] + sb[3];
  __syncthreads();
  return r;
}

// ---------------------------------------------------------------------------
// LayerNorm -> bf16 output. One block per row; handles both seq1 and seq2.
// ---------------------------------------------------------------------------
__global__ __launch_bounds__(256) void ln_kernel(
    const float* __restrict__ seq1, const float* __restrict__ seq2,
    const float* __restrict__ gamma, const float* __restrict__ beta,
    short* __restrict__ x1b, short* __restrict__ x2b) {
  int row = blockIdx.x;
  const int nrows = B_ * W_;
  bool first = row < nrows;
  const float* src = first ? seq1 : seq2;
  short* dst = first ? x1b : x2b;
  int r = first ? row : row - nrows;

  const float4* p = (const float4*)(src + (size_t)r * C_);
  float4 v = p[threadIdx.x];
  float mean = block_sum(v.x + v.y + v.z + v.w) * (1.0f / C_);
  float dx = v.x - mean, dy = v.y - mean, dz = v.z - mean, dw = v.w - mean;
  float var = block_sum(dx * dx + dy * dy + dz * dz + dw * dw) * (1.0f / C_);
  float rstd = rsqrtf(var + LN_EPS);

  float4 g = ((const float4*)gamma)[threadIdx.x];
  float4 b = ((const float4*)beta)[threadIdx.x];
  uint2 o;
  o.x = (unsigned)f2bf(dx * rstd * g.x + b.x) |
        ((unsigned)f2bf(dy * rstd * g.y + b.y) << 16);
  o.y = (unsigned)f2bf(dz * rstd * g.z + b.z) |
        ((unsigned)f2bf(dw * rstd * g.w + b.w) << 16);
  ((uint2*)(dst + (size_t)r * C_))[threadIdx.x] = o;
}

// ---------------------------------------------------------------------------
// Weight prep: proj [H,C,K] fp32 -> B^T bf16 [H*K rows][C cols], q scaled by
// 1/sqrt(K) (exact pow2). grid=(C/64, H, 3), block=256, LDS transpose.
// ---------------------------------------------------------------------------
__global__ __launch_bounds__(256) void wprep_proj_kernel(
    const float* __restrict__ qp, const float* __restrict__ kp,
    const float* __restrict__ vp,
    short* __restrict__ wqt, short* __restrict__ wkt, short* __restrict__ wvt) {
  int cb = blockIdx.x, h = blockIdx.y, which = blockIdx.z;
  const float* P = (which == 0 ? qp : (which == 1 ? kp : vp)) + (size_t)h * C_ * K_;
  short* Wt = (which == 0 ? wqt : (which == 1 ? wkt : wvt));
  float scale = (which == 0) ? 0.125f : 1.0f;

  __shared__ float Ls[64][65];
  int t = threadIdx.x;
  {
    int cr = t >> 2, ks = (t & 3) * 16;
    const float* src = P + (size_t)(cb * 64 + cr) * K_ + ks;
    #pragma unroll
    for (int j = 0; j < 4; ++j) {
      float4 v = *(const float4*)(src + j * 4);
      Ls[cr][ks + j * 4 + 0] = v.x; Ls[cr][ks + j * 4 + 1] = v.y;
      Ls[cr][ks + j * 4 + 2] = v.z; Ls[cr][ks + j * 4 + 3] = v.w;
    }
  }
  __syncthreads();
  int kr = t >> 2, cs = (t & 3) * 16;
  unsigned u[8];
  #pragma unroll
  for (int i = 0; i < 8; ++i) {
    float a = Ls[cs + 2 * i][kr] * scale;
    float b = Ls[cs + 2 * i + 1][kr] * scale;
    u[i] = (unsigned)f2bf(a) | ((unsigned)f2bf(b) << 16);
  }
  short* dst = Wt + ((size_t)h * 64 + kr) * C_ + cb * 64 + cs;
  uint4 p0; p0.x = u[0]; p0.y = u[1]; p0.z = u[2]; p0.w = u[3];
  uint4 p1; p1.x = u[4]; p1.y = u[5]; p1.z = u[6]; p1.w = u[7];
  *(uint4*)dst = p0;
  *(uint4*)(dst + 8) = p1;
}

// Mixer weight: plain fp32 -> bf16 (already in B^T form: out@W.T uses W[n][c]).
__global__ __launch_bounds__(256) void wprep_mix_kernel(
    const float* __restrict__ wm, short* __restrict__ wmb) {
  int gid = blockIdx.x * 256 + threadIdx.x;
  float4 v = ((const float4*)wm)[gid];
  uint2 o;
  o.x = (unsigned)f2bf(v.x) | ((unsigned)f2bf(v.y) << 16);
  o.y = (unsigned)f2bf(v.z) | ((unsigned)f2bf(v.w) << 16);
  ((uint2*)wmb)[gid] = o;
}

// ---------------------------------------------------------------------------
// bf16 MFMA GEMM core: C[128x128] tile of A[*,1024] x Bt[*,1024]^T.
// 256 threads = 4 waves (2x2), 16x16x32 MFMA, 4x4 frags/wave, BK=64.
// global_load_lds width-16 staging; XOR-swizzled LDS (conflict-free frags).
// ---------------------------------------------------------------------------
__device__ __forceinline__ void gemm_core(
    const short* __restrict__ A, const short* __restrict__ Bt,
    int arow0, int brow0, short* As, short* Bs, float4v acc[4][4]) {
  int tid = threadIdx.x;
  int wave = tid >> 6, lane = tid & 63;
  int lr = lane >> 3, lc = lane & 7;
  int sc = lc ^ lr;                       // swizzled global chunk for staging
  int wr = wave >> 1, wc = wave & 1;
  int lg = lane >> 4, ll = lane & 15;

  #pragma unroll
  for (int mi = 0; mi < 4; ++mi)
    #pragma unroll
    for (int ni = 0; ni < 4; ++ni) {
      acc[mi][ni][0] = 0.f; acc[mi][ni][1] = 0.f;
      acc[mi][ni][2] = 0.f; acc[mi][ni][3] = 0.f;
    }

  for (int k0 = 0; k0 < C_; k0 += 64) {
    __syncthreads();
    #pragma unroll
    for (int j = 0; j < 4; ++j) {
      int seg = wave * 4 + j;            // 8-row segment of the 128-row tile
      int r = seg * 8 + lr;
      gload_lds16(A + (size_t)(arow0 + r) * C_ + k0 + sc * 8, As + seg * 512);
      gload_lds16(Bt + (size_t)(brow0 + r) * C_ + k0 + sc * 8, Bs + seg * 512);
    }
    __syncthreads();
    #pragma unroll
    for (int kc = 0; kc < 2; ++kc) {
      int cc = kc * 4 + lg;
      short8 af[4], bf[4];
      #pragma unroll
      for (int mi = 0; mi < 4; ++mi) {
        int m = wr * 64 + mi * 16 + ll;
        af[mi] = *(const short8*)&As[m * 64 + ((cc ^ (m & 7)) << 3)];
      }
      #pragma unroll
      for (int ni = 0; ni < 4; ++ni) {
        int n = wc * 64 + ni * 16 + ll;
        bf[ni] = *(const short8*)&Bs[n * 64 + ((cc ^ (n & 7)) << 3)];
      }
      #pragma unroll
      for (int mi = 0; mi < 4; ++mi)
        #pragma unroll
        for (int ni = 0; ni < 4; ++ni)
          acc[mi][ni] = __builtin_amdgcn_mfma_f32_16x16x32_bf16(
              af[mi], bf[ni], acc[mi][ni], 0, 0, 0);
    }
  }
}

// ---------------------------------------------------------------------------
// QKV GEMMs, fused in grid.z: z=0 Q=x1@Wq^T, z=1 K=x2@Wk^T,
// z=2 V^T = Wv x2^T (operand-swapped so stores into [B,H,K,W] coalesce).
// Outputs bf16. grid=(32,8,3).
// ---------------------------------------------------------------------------
__global__ __launch_bounds__(256, 3) void gemm_qkv_kernel(
    const short* __restrict__ x1b, const short* __restrict__ x2b,
    const short* __restrict__ wqt, const short* __restrict__ wkt,
    const short* __restrict__ wvt,
    short* __restrict__ qb, short* __restrict__ kb, short* __restrict__ vtb) {
  __shared__ short As[128 * 64], Bs[128 * 64];
  int z = blockIdx.z;
  const short *A, *Bt;
  int arow0, brow0;
  if (z == 0)      { A = x1b; Bt = wqt; arow0 = blockIdx.x * 128; brow0 = blockIdx.y * 128; }
  else if (z == 1) { A = x2b; Bt = wkt; arow0 = blockIdx.x * 128; brow0 = blockIdx.y * 128; }
  else             { A = wvt; Bt = x2b; arow0 = blockIdx.y * 128; brow0 = blockIdx.x * 128; }

  float4v acc[4][4];
  gemm_core(A, Bt, arow0, brow0, As, Bs, acc);

  int wave = threadIdx.x >> 6, lane = threadIdx.x & 63;
  int wr = wave >> 1, wc = wave & 1, lg = lane >> 4, ll = lane & 15;
  if (z <= 1) {
    short* O = (z == 0) ? qb : kb;
    #pragma unroll
    for (int mi = 0; mi < 4; ++mi)
      #pragma unroll
      for (int ni = 0; ni < 4; ++ni) {
        int n = brow0 + wc * 64 + ni * 16 + ll;       // h*64+k
        int h = n >> 6, kk = n & 63;
        #pragma unroll
        for (int r2 = 0; r2 < 4; ++r2) {
          int m = arow0 + wr * 64 + mi * 16 + lg * 4 + r2;  // seq index
          int b = m >> 11, w = m & (W_ - 1);
          O[((size_t)(b * H_ + h) * W_ + w) * K_ + kk] = (short)f2bf(acc[mi][ni][r2]);
        }
      }
  } else {
    #pragma unroll
    for (int mi = 0; mi < 4; ++mi)
      #pragma unroll
      for (int ni = 0; ni < 4; ++ni) {
        int n = brow0 + wc * 64 + ni * 16 + ll;       // seq index
        int b = n >> 11, w = n & (W_ - 1);
        #pragma unroll
        for (int r2 = 0; r2 < 4; ++r2) {
          int m = arow0 + wr * 64 + mi * 16 + lg * 4 + r2;  // h*64+k
          int h = m >> 6, kk = m & 63;
          vtb[((size_t)(b * H_ + h) * K_ + kk) * W_ + w] = (short)f2bf(acc[mi][ni][r2]);
        }
      }
  }
}

// ---------------------------------------------------------------------------
// Mixer GEMM: out[4096,1024] fp32 = attnb @ wmb^T + bias. grid=(32,8).
// ---------------------------------------------------------------------------
__global__ __launch_bounds__(256, 3) void gemm_mix_kernel(
    const short* __restrict__ attnb, const short* __restrict__ wmb,
    const float* __restrict__ bias, float* __restrict__ out) {
  __shared__ short As[128 * 64], Bs[128 * 64];
  int arow0 = blockIdx.x * 128, brow0 = blockIdx.y * 128;
  float4v acc[4][4];
  gemm_core(attnb, wmb, arow0, brow0, As, Bs, acc);

  int wave = threadIdx.x >> 6, lane = threadIdx.x & 63;
  int wr = wave >> 1, wc = wave & 1, lg = lane >> 4, ll = lane & 15;
  #pragma unroll
  for (int mi = 0; mi < 4; ++mi)
    #pragma unroll
    for (int ni = 0; ni < 4; ++ni) {
      int n = brow0 + wc * 64 + ni * 16 + ll;
      float bv = bias[n];
      #pragma unroll
      for (int r2 = 0; r2 < 4; ++r2) {
        int m = arow0 + wr * 64 + mi * 16 + lg * 4 + r2;
        out[(size_t)m * C_ + n] = acc[mi][ni][r2] + bv;
      }
    }
}

// ---------------------------------------------------------------------------
// Causal flash attention, m97 skeleton + double-buffered K/V + balanced grid.
// grid=(32 bh, 32 slots), block=256 (4 waves x 16 q-rows = 64-q tile).
// Slot s -> qt = s<16 ? 31-s : s-16: CU-paired blocks' work sums constant
// (every CU does exactly 66 key-tile iters).
// K[64x64] / V^T[64x64] double-buffered via coalesced global_load_lds;
// raw barriers: s_waitcnt vmcnt(4)+s_barrier keeps the prefetch in flight
// across the barrier (AITER-style); lgkmcnt(0)+s_barrier releases the buffer
// without draining vmem.
// ---------------------------------------------------------------------------
__global__ __launch_bounds__(256, 3) void attn_mfma_kernel(
    const short* __restrict__ q, const short* __restrict__ k,
    const short* __restrict__ vt, short* __restrict__ out) {
  int bh = blockIdx.x;                    // 0..31
  int b = bh >> 4, h = bh & 15;
  int s = blockIdx.y;
  int qt = (s < 16) ? (31 - s) : (s - 16);  // balanced heavy/light pairing
  int wave = threadIdx.x >> 6;
  int lane = threadIdx.x & 63;
  int lg = lane >> 4, ll = lane & 15;

  __shared__ short Ks[2][64 * 64];        // [key][chan], swizzled chunks
  __shared__ short Vs[2][64 * 64];        // [chan][key], swizzled chunks
  __shared__ short Ps[4][16 * 76];        // per-wave P buffer

  const short* qp = q + (size_t)bh * W_ * K_;
  const short* kp = k + (size_t)bh * W_ * K_;
  const short* vb = vt + (size_t)bh * K_ * W_;

  // Q A-frags: wave owns rows qt*64 + wave*16 + ll
  int qrow = qt * 64 + wave * 16 + ll;
  short8 aq[2];
  #pragma unroll
  for (int kc = 0; kc < 2; ++kc)
    aq[kc] = *(const short8*)(qp + (size_t)qrow * K_ + kc * 32 + lg * 8);

  float4v o[4];
  #pragma unroll
  for (int ct = 0; ct < 4; ++ct) {
    o[ct][0] = 0.f; o[ct][1] = 0.f; o[ct][2] = 0.f; o[ct][3] = 0.f;
  }
  float m4[4], l4[4];
  #pragma unroll
  for (int r = 0; r < 4; ++r) { m4[r] = -INFINITY; l4[r] = 0.f; }

  int nkt = qt + 1;

  // stage key-tile kt into buffer buf (4 coalesced 16B loads per thread)
  #define STAGE(kt, buf)                                                   \
    {                                                                      \
      const short* kbase = kp + (size_t)(kt) * 64 * K_;                    \
      const short* vbase = vb + (kt) * 64;                                 \
      _Pragma("unroll")                                                    \
      for (int j = 0; j < 2; ++j) {                                        \
        int sdx = j * 256 + (int)threadIdx.x;                              \
        int m = sdx >> 3, c7 = sdx & 7;                                    \
        int gc = c7 ^ (m & 7);                                             \
        gload_lds16(kbase + (size_t)m * K_ + gc * 8, &Ks[buf][sdx * 8]);   \
        gload_lds16(vbase + (size_t)m * W_ + gc * 8, &Vs[buf][sdx * 8]);   \
      }                                                                    \
    }

  STAGE(0, 0);
  for (int kt = 0; kt < nkt; ++kt) {
    int cur = kt & 1;
    if (kt + 1 < nkt) {
      STAGE(kt + 1, cur ^ 1);
      // wait only the current buffer's 4 loads; prefetch stays in flight
      asm volatile("s_waitcnt vmcnt(4)\ns_barrier" ::: "memory");
    } else {
      asm volatile("s_waitcnt vmcnt(0)\ns_barrier" ::: "memory");
    }

    // ---- S = Q.K^T ----
    float4v st[4];
    #pragma unroll
    for (int nt = 0; nt < 4; ++nt) {
      st[nt][0] = 0.f; st[nt][1] = 0.f; st[nt][2] = 0.f; st[nt][3] = 0.f;
      int n = nt * 16 + ll;
      #pragma unroll
      for (int kc = 0; kc < 2; ++kc) {
        int cc = kc * 4 + lg;
        short8 bk = *(const short8*)&Ks[cur][n * 64 + ((cc ^ (n & 7)) << 3)];
        st[nt] = __builtin_amdgcn_mfma_f32_16x16x32_bf16(aq[kc], bk, st[nt], 0, 0, 0);
      }
    }
    // ---- V^T B-frags ----
    short8 bv[4][2];
    #pragma unroll
    for (int ct = 0; ct < 4; ++ct) {
      int c = ct * 16 + ll;
      #pragma unroll
      for (int kc = 0; kc < 2; ++kc) {
        int cc = kc * 4 + lg;
        bv[ct][kc] = *(const short8*)&Vs[cur][c * 64 + ((cc ^ (c & 7)) << 3)];
      }
    }

    float sv[4][4];
    #pragma unroll
    for (int nt = 0; nt < 4; ++nt)
      #pragma unroll
      for (int r = 0; r < 4; ++r) sv[nt][r] = st[nt][r];
    if (kt == qt) {  // diagonal tile: causal mask
      int rowb = qt * 64 + wave * 16 + lg * 4;
      #pragma unroll
      for (int nt = 0; nt < 4; ++nt) {
        int key = kt * 64 + nt * 16 + ll;
        #pragma unroll
        for (int r = 0; r < 4; ++r)
          if (key > rowb + r) sv[nt][r] = -INFINITY;
      }
    }
    // ---- online softmax: stats per row (lg*4+r), reduce over 16 ll lanes ----
    float pv[4][4];
    #pragma unroll
    for (int r = 0; r < 4; ++r) {
      float x = fmaxf(fmaxf(sv[0][r], sv[1][r]), fmaxf(sv[2][r], sv[3][r]));
      x = fmaxf(x, __shfl_xor(x, 1, 64));
      x = fmaxf(x, __shfl_xor(x, 2, 64));
      x = fmaxf(x, __shfl_xor(x, 4, 64));
      x = fmaxf(x, __shfl_xor(x, 8, 64));
      float nm = fmaxf(m4[r], x);
      float al = __expf(m4[r] - nm);  // first tile: exp(-inf)=0
      m4[r] = nm;
      float ps = 0.f;
      #pragma unroll
      for (int nt = 0; nt < 4; ++nt) {
        float e = __expf(sv[nt][r] - nm);
        pv[nt][r] = e;
        ps += e;
      }
      ps += __shfl_xor(ps, 1, 64);
      ps += __shfl_xor(ps, 2, 64);
      ps += __shfl_xor(ps, 4, 64);
      ps += __shfl_xor(ps, 8, 64);
      l4[r] = l4[r] * al + ps;
      #pragma unroll
      for (int ct = 0; ct < 4; ++ct) o[ct][r] *= al;
    }
    // ---- P (C-layout) -> bf16 -> wave-private LDS -> A-layout ----
    short* myP = &Ps[wave][0];
    #pragma unroll
    for (int nt = 0; nt < 4; ++nt)
      #pragma unroll
      for (int r = 0; r < 4; ++r)
        myP[(lg * 4 + r) * 76 + nt * 16 + ll] = (short)f2bf(pv[nt][r]);
    __builtin_amdgcn_s_waitcnt(0xC07F);  // lgkmcnt(0), wave-private
    short8 ap[2];
    ap[0] = *(const short8*)(myP + ll * 76 + lg * 8);
    ap[1] = *(const short8*)(myP + ll * 76 + 32 + lg * 8);
    // ---- O += P.V ----
    #pragma unroll
    for (int ct = 0; ct < 4; ++ct) {
      o[ct] = __builtin_amdgcn_mfma_f32_16x16x32_bf16(ap[0], bv[ct][0], o[ct], 0, 0, 0);
      o[ct] = __builtin_amdgcn_mfma_f32_16x16x32_bf16(ap[1], bv[ct][1], o[ct], 0, 0, 0);
    }
    // release current buffer for the next-next stage; do NOT drain vmem
    asm volatile("s_waitcnt lgkmcnt(0)\ns_barrier" ::: "memory");
  }
  #undef STAGE

  // ---- epilogue: normalize, write bf16 [B,W,C] ----
  float inv[4];
  #pragma unroll
  for (int r = 0; r < 4; ++r) inv[r] = 1.0f / l4[r];
  #pragma unroll
  for (int ct = 0; ct < 4; ++ct)
    #pragma unroll
    for (int r = 0; r < 4; ++r) {
      int row = qt * 64 + wave * 16 + lg * 4 + r;
      out[((size_t)(b * W_ + row)) * C_ + h * K_ + ct * 16 + ll] =
          (short)f2bf(o[ct][r] * inv[r]);
    }
}

// ---------------------------------------------------------------------------
extern "C" void kernel_launch(void* const* d_in, const int* in_sizes, int n_in,
                              void* d_out, int out_size, void* d_ws, size_t ws_size,
                              hipStream_t stream) {
  const float* seq1  = (const float*)d_in[0];
  const float* seq2  = (const float*)d_in[1];
  const float* gamma = (const float*)d_in[2];
  const float* beta  = (const float*)d_in[3];
  const float* qp    = (const float*)d_in[4];
  const float* kp    = (const float*)d_in[5];
  const float* vp    = (const float*)d_in[6];
  const float* wm    = (const float*)d_in[7];
  const float* mb    = (const float*)d_in[8];
  float* out = (float*)d_out;

  char* ws = (char*)d_ws;
  const size_t NROW = (size_t)B_ * W_;               // 4096
  const size_t XB = NROW * C_ * sizeof(short);       // 8 MB bf16 activation buf
  const size_t WB = (size_t)C_ * C_ * sizeof(short); // 2 MB bf16 weight buf
  short* x1b = (short*)(ws);
  short* x2b = (short*)(ws + XB);
  short* qb  = (short*)(ws + 2 * XB);
  short* kb  = (short*)(ws + 3 * XB);
  short* vtb = (short*)(ws + 4 * XB);
  short* wqt = (short*)(ws + 5 * XB);
  short* wkt = (short*)(ws + 5 * XB + WB);
  short* wvt = (short*)(ws + 5 * XB + 2 * WB);
  short* wmb = (short*)(ws + 5 * XB + 3 * WB);
  short* attnb = (short*)(ws + 5 * XB + 4 * WB);

  wprep_proj_kernel<<<dim3(C_ / 64, H_, 3), dim3(256), 0, stream>>>(
      qp, kp, vp, wqt, wkt, wvt);
  wprep_mix_kernel<<<dim3(C_ * C_ / 1024), dim3(256), 0, stream>>>(wm, wmb);
  ln_kernel<<<dim3(2 * (unsigned)NROW), dim3(256), 0, stream>>>(
      seq1, seq2, gamma, beta, x1b, x2b);
  gemm_qkv_kernel<<<dim3(32, 8, 3), dim3(256), 0, stream>>>(
      x1b, x2b, wqt, wkt, wvt, qb, kb, vtb);
  attn_mfma_kernel<<<dim3(32, 32), dim3(256), 0, stream>>>(
      qb, kb, vtb, attnb);
  gemm_mix_kernel<<<dim3(32, 8), dim3(256), 0, stream>>>(attnb, wmb, mb, out);
}